// Round 1
// baseline (893.649 us; speedup 1.0000x reference)
//
#include <hip/hip_runtime.h>
#include <math.h>

#define TT 1600
#define BB 48
#define VV 1000
#define LL 128
#define EMS 132   // compact emission row: [0]=blank, [2..129]=labels, 16B-aligned stride

// ---------------------------------------------------------------------------
// K1: fully parallel gather+exp. One wave per (t,b) row.
// em[row][0]     = exp(lp[t,b,0])                (blank)
// em[row][2 + j] = exp(lp[t,b,tg[b][j]]), j=0..127
// ---------------------------------------------------------------------------
__global__ __launch_bounds__(256) void ctc_gather_kernel(
    const float* __restrict__ lp,
    const int* __restrict__ targets,
    float* __restrict__ em)
{
  int gid  = blockIdx.x * 256 + threadIdx.x;
  int wid  = gid >> 6;
  int lane = threadIdx.x & 63;
  if (wid >= TT * BB) return;
  int b = wid % BB;
  const float* __restrict__ row  = lp + (size_t)wid * VV;
  float* __restrict__       erow = em + (size_t)wid * EMS;
  const int* __restrict__   tg   = targets + b * LL;
  for (int k = lane; k < 129; k += 64) {
    int lab = (k == 0) ? 0 : tg[k - 1];
    int pos = (k == 0) ? 0 : (k + 1);
    erow[pos] = __expf(row[lab]);
  }
}

// ---------------------------------------------------------------------------
// K2: linear-domain scaled CTC forward. One wave per batch element.
// State mapping: s = 4*lane + r (r=0..3), plus s=256 as a4 on lane 63.
// Only cross-lane dependency per step: alpha_old[4l-1] = lane(l-1).a3.
// ---------------------------------------------------------------------------
__global__ __launch_bounds__(64) void ctc_dp_kernel(
    const float* __restrict__ em,
    const int* __restrict__ targets,
    const int* __restrict__ input_lengths,
    float* __restrict__ out)
{
  const int b    = blockIdx.x;
  const int lane = threadIdx.x;
  const int Tlen = input_lengths[b];
  const int NS   = Tlen - 1;            // steps t = 1..NS

  const int* __restrict__ tg = targets + b * LL;
  const int c0  = tg[2 * lane];                       // label of state 4l+1
  const int c1  = tg[2 * lane + 1];                   // label of state 4l+3
  const int cm1 = (lane > 0) ? tg[2 * lane - 1] : c0; // label of state 4l-1
  const float skip1 = (lane > 0 && c0 != cm1) ? 1.0f : 0.0f;  // s=4l+1 skip
  const float skip3 = (c1 != c0) ? 1.0f : 0.0f;               // s=4l+3 skip
  const float m63   = (lane == 63) ? 1.0f : 0.0f;

  const size_t rowstep = (size_t)BB * EMS;
  const float* __restrict__ base = em + (size_t)b * EMS;

  // t=0 init: alpha[0] = p_blank(0), alpha[1] = p_tg0(0), rest 0
  float a0 = 0.f, a1 = 0.f, a2 = 0.f, a3 = 0.f, a4 = 0.f;
  if (lane == 0) { a0 = base[0]; a1 = base[2]; }
  int esum = 0;

  float  pbuf[8];
  float2 ebuf[8];

#define ISSUE(SLOT, TF) do {                                         \
    const float* r_ = base + (size_t)(TF) * rowstep;                 \
    pbuf[SLOT] = r_[0];                                              \
    ebuf[SLOT] = *(const float2*)(r_ + 2 + 2 * lane);                \
  } while (0)

#define STEP(SLOT) do {                                              \
    float pb  = pbuf[SLOT];                                          \
    float2 ev = ebuf[SLOT];                                          \
    float am1 = __shfl_up(a3, 1);        /* alpha_old[4l-1] */       \
    if (lane == 0) am1 = 0.f;                                        \
    float n0 = (a0 + am1) * pb;                                      \
    float n1 = (a1 + a0 + skip1 * am1) * ev.x;                       \
    float n2 = (a2 + a1) * pb;                                       \
    float n3 = (a3 + a2 + skip3 * a1) * ev.y;                        \
    float n4 = (a4 + a3 * m63) * pb;     /* state 256 (lane 63) */   \
    a0 = n0; a1 = n1; a2 = n2; a3 = n3; a4 = n4;                     \
  } while (0)

#define RESCALE() do {                                               \
    float mx = fmaxf(fmaxf(a0, a1), fmaxf(a2, a3));                  \
    mx = fmaxf(mx, a4);                                              \
    mx = fmaxf(mx, __shfl_xor(mx, 32));                              \
    mx = fmaxf(mx, __shfl_xor(mx, 16));                              \
    mx = fmaxf(mx, __shfl_xor(mx, 8));                               \
    mx = fmaxf(mx, __shfl_xor(mx, 4));                               \
    mx = fmaxf(mx, __shfl_xor(mx, 2));                               \
    mx = fmaxf(mx, __shfl_xor(mx, 1));                               \
    int ee; (void)frexpf(mx, &ee);                                   \
    float sc = ldexpf(1.0f, -ee);                                    \
    a0 *= sc; a1 *= sc; a2 *= sc; a3 *= sc; a4 *= sc;                \
    esum += ee;                                                      \
  } while (0)

  // prologue: prefetch first 8 steps
#pragma unroll
  for (int d = 0; d < 8; d++) {
    if (d < NS) ISSUE(d, 1 + d);
  }

  int t = 1;
  const int nb = NS >> 3;
  for (int ib = 0; ib < nb; ib++) {
#pragma unroll
    for (int d = 0; d < 8; d++) {
      STEP(d);
      int tf = t + 8;
      if (tf <= NS) ISSUE(d, tf);
      t++;
      if ((d & 3) == 3) RESCALE();
    }
  }
  const int rem = NS & 7;
#pragma unroll
  for (int d = 0; d < 8; d++) {
    if (d < rem) STEP(d);
  }

  if (lane == 63) {
    // final states: alpha[255] = a3, alpha[256] = a4
    float tot = __logf(a3 + a4) + (float)esum * 0.69314718055994530942f;
    atomicAdd(out, -tot);
  }

#undef ISSUE
#undef STEP
#undef RESCALE
}

// ---------------------------------------------------------------------------
extern "C" void kernel_launch(void* const* d_in, const int* in_sizes, int n_in,
                              void* d_out, int out_size, void* d_ws, size_t ws_size,
                              hipStream_t stream) {
  const float* lp            = (const float*)d_in[0];
  const int*   targets       = (const int*)d_in[1];
  const int*   input_lengths = (const int*)d_in[2];
  // d_in[3] = target_lengths, all == LL by construction

  float* em  = (float*)d_ws;          // TT*BB*EMS floats = ~40.6 MB
  float* out = (float*)d_out;

  hipMemsetAsync(out, 0, sizeof(float), stream);

  const int rows   = TT * BB;          // 76800 waves, 4 per block
  const int blocks = rows / 4;         // 19200
  ctc_gather_kernel<<<blocks, 256, 0, stream>>>(lp, targets, em);
  ctc_dp_kernel<<<BB, 64, 0, stream>>>(em, targets, input_lengths, out);
}

// Round 2
// 652.851 us; speedup vs baseline: 1.3688x; 1.3688x over previous
//
#include <hip/hip_runtime.h>
#include <math.h>

#define TT 1600
#define BB 48
#define VV 1000
#define LL 128
#define EMS 132                       // emission row: [0]=blank, [2..129]=labels
#define EMTOT (TT*EMS)                // floats per batch element (211200)
#define TILE 60                       // timesteps per LDS tile
#define TILEF (TILE*EMS)              // 7920 floats = 31680 B per tile
#define NTILES ((TT + TILE - 1)/TILE) // 27

// ---------------------------------------------------------------------------
// K1: coalesced row load -> LDS -> gather+exp. One wave per (t,b) row.
// em layout: [B][T][EMS].  em[b][t][0] = p_blank, em[b][t][2+j] = p(tg[b][j]).
// ---------------------------------------------------------------------------
__global__ __launch_bounds__(256) void ctc_gather_kernel(
    const float* __restrict__ lp,
    const int* __restrict__ targets,
    float* __restrict__ em)
{
  __shared__ float rowbuf[4][1024];
  const int wv   = threadIdx.x >> 6;
  const int lane = threadIdx.x & 63;
  const int wid  = blockIdx.x * 4 + wv;        // row id = t*BB + b
  const int t    = wid / BB;
  const int b    = wid - t * BB;

  const float* __restrict__ row = lp + (size_t)wid * VV;
  float* rb = rowbuf[wv];
#pragma unroll
  for (int i = 0; i < 4; i++) {
    int idx = lane + 64 * i;                   // 250 float4 = 1000 floats
    if (idx < 250) ((float4*)rb)[idx] = ((const float4*)row)[idx];
  }
  __syncthreads();

  const int* __restrict__ tg = targets + b * LL;
  float* __restrict__ erow = em + (size_t)b * EMTOT + (size_t)t * EMS;
#pragma unroll
  for (int ii = 0; ii < 3; ii++) {
    int k = lane + 64 * ii;
    if (k < 129) {
      int lab = (k == 0) ? 0 : tg[k - 1];
      int pos = (k == 0) ? 0 : (k + 1);
      erow[pos] = __expf(rb[lab]);
    }
  }
}

// ---------------------------------------------------------------------------
// K2: linear-domain scaled CTC forward. One block (2 waves) per batch element.
// Wave 1: streams 60-step emission tiles into double-buffered LDS.
// Wave 0: DP recurrence, states s = 4*lane + r (+ s=256 as a4 on lane 63).
// ---------------------------------------------------------------------------
__global__ __launch_bounds__(128) void ctc_dp_kernel(
    const float* __restrict__ em,
    const int* __restrict__ targets,
    const int* __restrict__ input_lengths,
    float* __restrict__ out)
{
  __shared__ float sbuf[2][TILEF];             // 63360 B
  const int b    = blockIdx.x;
  const int lane = threadIdx.x & 63;
  const int wv   = threadIdx.x >> 6;
  const int NS   = input_lengths[b] - 1;       // steps t = 1..NS
  const float* __restrict__ base = em + (size_t)b * EMTOT;

  // ----- consumer lane-local constants -----
  float skip1 = 0.f, skip3 = 0.f, m63 = 0.f;
  if (wv == 0) {
    const int* __restrict__ tg = targets + b * LL;
    const int c0  = tg[2 * lane];
    const int c1  = tg[2 * lane + 1];
    const int cm1 = (lane > 0) ? tg[2 * lane - 1] : c0;
    skip1 = (lane > 0 && c0 != cm1) ? 1.0f : 0.0f;
    skip3 = (c1 != c0) ? 1.0f : 0.0f;
    m63   = (lane == 63) ? 1.0f : 0.0f;
  }

  float a0 = 0.f, a1 = 0.f, a2 = 0.f, a3 = 0.f, a4 = 0.f;
  int esum = 0;
  float  pb_r[4];
  float2 ev_r[4];

  // ----- producer: stage tile 0 -----
  if (wv == 1) {
    const float4* src = (const float4*)base;
    float4* dst = (float4*)sbuf[0];
    for (int j = 0; j < 31; j++) {
      int idx = j * 64 + lane;
      if (idx < (TILEF >> 2)) dst[idx] = src[idx];
    }
  }
  __syncthreads();

#define STEP(PB, EV) do {                                            \
    float am1 = __shfl_up(a3, 1);                                    \
    am1 = (lane == 0) ? 0.f : am1;                                   \
    float s0 = a0 + am1;                                             \
    float s1 = fmaf(skip1, am1, a0 + a1);                            \
    float s2 = a1 + a2;                                              \
    float s3 = fmaf(skip3, a1, a2 + a3);                             \
    float s4 = fmaf(a3, m63, a4);                                    \
    a0 = s0 * (PB); a1 = s1 * (EV).x; a2 = s2 * (PB);                \
    a3 = s3 * (EV).y; a4 = s4 * (PB);                                \
  } while (0)

#define RESCALE() do {                                               \
    float mx = fmaxf(fmaxf(fmaxf(a0, a1), fmaxf(a2, a3)), a4);       \
    mx = fmaxf(mx, __shfl_xor(mx, 32));                              \
    mx = fmaxf(mx, __shfl_xor(mx, 16));                              \
    mx = fmaxf(mx, __shfl_xor(mx, 8));                               \
    mx = fmaxf(mx, __shfl_xor(mx, 4));                               \
    mx = fmaxf(mx, __shfl_xor(mx, 2));                               \
    mx = fmaxf(mx, __shfl_xor(mx, 1));                               \
    int eb = (int)((__float_as_uint(mx) >> 23) & 0xFF);              \
    int se = 157 - eb;   /* scale max to ~2^30 */                    \
    se = se < -126 ? -126 : (se > 127 ? 127 : se);                   \
    float sc = __uint_as_float((unsigned)(se + 127) << 23);          \
    a0 *= sc; a1 *= sc; a2 *= sc; a3 *= sc; a4 *= sc;                \
    esum -= se;                                                      \
  } while (0)

  for (int k = 0; k < NTILES; k++) {
    if (wv == 1) {
      // ----- producer: stage tile k+1 into sbuf[(k+1)&1] -----
      int kn = k + 1;
      if (kn < NTILES) {
        const float4* src = (const float4*)(base + (size_t)kn * TILEF);
        float4* dst = (float4*)sbuf[kn & 1];
        int f4cnt = (EMTOT - kn * TILEF);
        f4cnt = (f4cnt > TILEF ? TILEF : f4cnt) >> 2;
        for (int j = 0; j < 31; j++) {
          int idx = j * 64 + lane;
          if (idx < f4cnt) dst[idx] = src[idx];
        }
      }
    } else {
      // ----- consumer: tile k from sbuf[k&1] -----
      const float* lb = sbuf[k & 1];
      if (k == 0 && lane == 0) { a0 = lb[0]; a1 = lb[2]; }  // t=0 init
      int tbeg = (k == 0) ? 1 : k * TILE;
      int tend = k * TILE + TILE - 1;
      if (tend > NS) tend = NS;
      int n = tend - tbeg + 1;
      if (n > 0) {
        const int loc0 = tbeg - k * TILE;      // 1 for k=0 else 0
        const float* lb0 = lb + loc0 * EMS;
        const float* lbe = lb0 + 2 + 2 * lane;
#define LOADSLOT(D, TF) do {                                         \
    int off_ = (TF) * EMS;                                           \
    pb_r[D] = lb0[off_];                                             \
    ev_r[D] = *(const float2*)(lbe + off_);                          \
  } while (0)
#pragma unroll
        for (int d = 0; d < 4; d++) { if (d < n) LOADSLOT(d, d); }
        int i = 0;
        while (i + 4 <= n) {
#pragma unroll
          for (int d = 0; d < 4; d++) {
            STEP(pb_r[d], ev_r[d]);
            int tf = i + 4 + d;
            if (tf < n) LOADSLOT(d, tf);
          }
          RESCALE();
          i += 4;
        }
#pragma unroll
        for (int d = 0; d < 3; d++) {
          if (i + d < n) STEP(pb_r[d], ev_r[d]);
        }
        if (i < n) RESCALE();
#undef LOADSLOT
      }
    }
    __syncthreads();
  }

  if (wv == 0 && lane == 63) {
    // alpha[255] = a3, alpha[256] = a4 (true value = stored * 2^esum)
    float tot = __logf(a3 + a4) + (float)esum * 0.69314718055994530942f;
    atomicAdd(out, -tot);
  }
#undef STEP
#undef RESCALE
}

// ---------------------------------------------------------------------------
extern "C" void kernel_launch(void* const* d_in, const int* in_sizes, int n_in,
                              void* d_out, int out_size, void* d_ws, size_t ws_size,
                              hipStream_t stream) {
  const float* lp            = (const float*)d_in[0];
  const int*   targets       = (const int*)d_in[1];
  const int*   input_lengths = (const int*)d_in[2];

  float* em  = (float*)d_ws;                   // BB*EMTOT floats = ~40.6 MB
  float* out = (float*)d_out;

  hipMemsetAsync(out, 0, sizeof(float), stream);

  const int blocks = (TT * BB) / 4;            // 19200 blocks, 4 rows each
  ctc_gather_kernel<<<blocks, 256, 0, stream>>>(lp, targets, em);
  ctc_dp_kernel<<<BB, 128, 0, stream>>>(em, targets, input_lengths, out);
}

// Round 3
// 563.281 us; speedup vs baseline: 1.5865x; 1.1590x over previous
//
#include <hip/hip_runtime.h>
#include <math.h>

#define TT 1600
#define BB 48
#define VV 1000
#define LL 128
#define EMS 132                       // emission row: [0]=blank, [2..129]=labels
#define EMTOT (TT*EMS)                // floats per batch element (211200)
#define TILE 60                       // timesteps per LDS tile
#define TILEF (TILE*EMS)              // 7920 floats = 31680 B per tile
#define NTILES 27                     // 26 full + 1 partial (40 rows)

// DPP helper: pure-VALU cross-lane, no LDS counter traffic.
#define DPPF(x, ctrl) __int_as_float(__builtin_amdgcn_update_dpp( \
    0, __float_as_int(x), (ctrl), 0xf, 0xf, true))

// ---------------------------------------------------------------------------
// K1: direct scattered gather + exp. One wave per (b, 4 consecutive t).
// em layout [B][T][EMS]: em[b][t][0]=p_blank, em[b][t][2+j]=p(tg[b][j]).
// Lane k covers gather indices k, k+64 (and lane0: 128).
// ---------------------------------------------------------------------------
__global__ __launch_bounds__(256) void ctc_gather_kernel(
    const float* __restrict__ lp,
    const int* __restrict__ targets,
    float* __restrict__ em)
{
  const int wv   = threadIdx.x >> 6;
  const int lane = threadIdx.x & 63;
  const int gw   = blockIdx.x * 4 + wv;        // 0..19199
  const int b    = gw % BB;
  const int t0   = (gw / BB) * 4;

  const int* __restrict__ tg = targets + b * LL;
  const int g0 = (lane == 0) ? 0 : tg[lane - 1];   // label for gather idx k=lane
  const int g1 = tg[lane + 63];                    // k = lane+64
  const int g2 = tg[127];                          // k = 128 (lane 0 only)
  const int p0 = (lane == 0) ? 0 : (lane + 1);
  const int p1 = lane + 65;

  float v0[4], v1[4], v2[4];
#pragma unroll
  for (int r = 0; r < 4; r++) {
    const float* row = lp + ((size_t)(t0 + r) * BB + b) * VV;
    v0[r] = row[g0];
    v1[r] = row[g1];
    if (lane == 0) v2[r] = row[g2];
  }
#pragma unroll
  for (int r = 0; r < 4; r++) {
    float* erow = em + (size_t)b * EMTOT + (size_t)(t0 + r) * EMS;
    erow[p0] = __expf(v0[r]);
    erow[p1] = __expf(v1[r]);
    if (lane == 0) erow[129] = __expf(v2[r]);
  }
}

// ---------------------------------------------------------------------------
// K2: linear-domain scaled CTC forward. One block (2 waves) per batch element.
// Wave 1: async-stages 60-step emission tiles (global_load_lds, dbuf LDS).
// Wave 0: DP recurrence, states s = 4*lane + r (+ s=256 as a4 on lane 63).
// Cross-lane shift done with DPP row_shr:1 + bcast15/31 fixups (no lgkmcnt).
// ---------------------------------------------------------------------------
__global__ __launch_bounds__(128) void ctc_dp_kernel(
    const float* __restrict__ em,
    const int* __restrict__ targets,
    const int* __restrict__ input_lengths,
    float* __restrict__ out)
{
  __shared__ float sbuf[2][TILEF];             // 63360 B
  const int b    = blockIdx.x;
  const int lane = threadIdx.x & 63;
  const int wv   = threadIdx.x >> 6;
  const int NS   = input_lengths[b] - 1;       // steps t = 1..NS
  const float* __restrict__ base = em + (size_t)b * EMTOT;

  // ----- consumer lane-local constants -----
  float skip1 = 0.f, skip3 = 0.f, m63 = 0.f, sel1648 = 0.f, sel32 = 0.f;
  if (wv == 0) {
    const int* __restrict__ tg = targets + b * LL;
    const int c0  = tg[2 * lane];
    const int c1  = tg[2 * lane + 1];
    const int cm1 = (lane > 0) ? tg[2 * lane - 1] : c0;
    skip1   = (lane > 0 && c0 != cm1) ? 1.0f : 0.0f;
    skip3   = (c1 != c0) ? 1.0f : 0.0f;
    m63     = (lane == 63) ? 1.0f : 0.0f;
    sel1648 = (lane == 16 || lane == 48) ? 1.0f : 0.0f;
    sel32   = (lane == 32) ? 1.0f : 0.0f;
  }

  float a0 = 0.f, a1 = 0.f, a2 = 0.f, a3 = 0.f, a4 = 0.f;
  int esum = 0;
  float  pb_r[4];
  float2 ev_r[4];

#define STAGE(KN) do {                                               \
    const float4* src_ = (const float4*)(base + (size_t)(KN) * TILEF); \
    float* dst_ = sbuf[(KN) & 1];                                    \
    const int nf4_ = ((KN) == NTILES - 1) ? 1320 : 1980;             \
    _Pragma("unroll")                                                \
    for (int j = 0; j < 31; j++) {                                   \
      int idx_ = (j << 6) + lane;                                    \
      if (idx_ < nf4_)                                               \
        __builtin_amdgcn_global_load_lds(                            \
            (const __attribute__((address_space(1))) unsigned int*)(src_ + idx_), \
            (__attribute__((address_space(3))) unsigned int*)(dst_ + (j << 8)),   \
            16, 0, 0);                                               \
    }                                                                \
  } while (0)

  // alpha_old[4l-1]: DPP row_shr:1 (lanes 0/16/32/48 -> 0), then patch
  // lane16/48 from bcast15 (15->16..31, 47->48..63) and lane32 from bcast31.
#define STEP(PB, EV) do {                                            \
    float am1 = DPPF(a3, 0x111);         /* row_shr:1  */            \
    float h15 = DPPF(a3, 0x142);         /* row_bcast15 */           \
    float h31 = DPPF(a3, 0x143);         /* row_bcast31 */           \
    am1 = fmaf(sel1648, h15, am1);                                   \
    am1 = fmaf(sel32,   h31, am1);                                   \
    float s0 = a0 + am1;                                             \
    float s1 = fmaf(skip1, am1, a0 + a1);                            \
    float s2 = a1 + a2;                                              \
    float s3 = fmaf(skip3, a1, a2 + a3);                             \
    float s4 = fmaf(a3, m63, a4);                                    \
    a0 = s0 * (PB); a1 = s1 * (EV).x; a2 = s2 * (PB);                \
    a3 = s3 * (EV).y; a4 = s4 * (PB);                                \
  } while (0)

  // Uniform power-of-2 rescale; max-reduce entirely on the VALU via DPP.
#define RESCALE() do {                                               \
    float mx = fmaxf(fmaxf(fmaxf(a0, a1), fmaxf(a2, a3)), a4);       \
    mx = fmaxf(mx, DPPF(mx, 0x111));     /* row_shr:1 */             \
    mx = fmaxf(mx, DPPF(mx, 0x112));     /* row_shr:2 */             \
    mx = fmaxf(mx, DPPF(mx, 0x114));     /* row_shr:4 */             \
    mx = fmaxf(mx, DPPF(mx, 0x118));     /* row_shr:8 */             \
    mx = fmaxf(mx, DPPF(mx, 0x142));     /* bcast15 */               \
    mx = fmaxf(mx, DPPF(mx, 0x143));     /* bcast31 -> lane63 = max */ \
    int eb = (__builtin_amdgcn_readlane(__float_as_int(mx), 63) >> 23) & 0xFF; \
    int se = 157 - eb;                   /* scale max to ~2^30 */    \
    se = se < -126 ? -126 : (se > 127 ? 127 : se);                   \
    float sc = __uint_as_float((unsigned)(se + 127) << 23);          \
    a0 *= sc; a1 *= sc; a2 *= sc; a3 *= sc; a4 *= sc;                \
    esum -= se;                                                      \
  } while (0)

  if (wv == 1) STAGE(0);
  __syncthreads();

  for (int k = 0; k < NTILES; k++) {
    if (wv == 1) {
      if (k + 1 < NTILES) STAGE(k + 1);
    } else {
      const float* lb = sbuf[k & 1];
      if (k == 0 && lane == 0) { a0 = lb[0]; a1 = lb[2]; }  // t=0 init
      int tbeg = (k == 0) ? 1 : k * TILE;
      int tend = k * TILE + TILE - 1;
      if (tend > NS) tend = NS;
      int n = tend - tbeg + 1;
      if (n > 0) {
        const float* lb0 = lb + (tbeg - k * TILE) * EMS;
        const float* lbe = lb0 + 2 + 2 * lane;
#define LOADSLOT(D, TF) do {                                         \
    int off_ = (TF) * EMS;                                           \
    pb_r[D] = lb0[off_];                                             \
    ev_r[D] = *(const float2*)(lbe + off_);                          \
  } while (0)
#pragma unroll
        for (int d = 0; d < 4; d++) { if (d < n) LOADSLOT(d, d); }
        int i = 0;
        while (i + 4 <= n) {
#pragma unroll
          for (int d = 0; d < 4; d++) {
            STEP(pb_r[d], ev_r[d]);
            int tf = i + 4 + d;
            if (tf < n) LOADSLOT(d, tf);
          }
          RESCALE();
          i += 4;
        }
#pragma unroll
        for (int d = 0; d < 3; d++) {
          if (i + d < n) STEP(pb_r[d], ev_r[d]);
        }
        if (i < n) RESCALE();
#undef LOADSLOT
      }
    }
    __syncthreads();
  }

  if (wv == 0 && lane == 63) {
    // alpha[255] = a3, alpha[256] = a4 (true value = stored * 2^esum)
    float tot = __logf(a3 + a4) + (float)esum * 0.69314718055994530942f;
    atomicAdd(out, -tot);
  }
#undef STEP
#undef RESCALE
#undef STAGE
}

// ---------------------------------------------------------------------------
extern "C" void kernel_launch(void* const* d_in, const int* in_sizes, int n_in,
                              void* d_out, int out_size, void* d_ws, size_t ws_size,
                              hipStream_t stream) {
  const float* lp            = (const float*)d_in[0];
  const int*   targets       = (const int*)d_in[1];
  const int*   input_lengths = (const int*)d_in[2];

  float* em  = (float*)d_ws;                   // BB*EMTOT floats = ~40.6 MB
  float* out = (float*)d_out;

  hipMemsetAsync(out, 0, sizeof(float), stream);

  ctc_gather_kernel<<<4800, 256, 0, stream>>>(lp, targets, em);
  ctc_dp_kernel<<<BB, 128, 0, stream>>>(em, targets, input_lengths, out);
}

// Round 4
// 557.527 us; speedup vs baseline: 1.6029x; 1.0103x over previous
//
#include <hip/hip_runtime.h>
#include <math.h>

#define TT 1600
#define BB 48
#define VV 1000
#define LL 128
#define EMS 132                       // emission row: [0]=blank, [2..129]=labels
#define EMTOT (TT*EMS)                // floats per batch element (211200)
#define TILE 60                       // timesteps per LDS tile
#define TILEF (TILE*EMS)              // 7920 floats = 31680 B per tile
#define NTILES 27                     // 26 full + 1 partial (40 rows)

// DPP helper: pure-VALU cross-lane, no LDS counter traffic.
#define DPPF(x, ctrl) __int_as_float(__builtin_amdgcn_update_dpp( \
    0, __float_as_int(x), (ctrl), 0xf, 0xf, true))

typedef const __attribute__((address_space(1))) unsigned int* gldlds_src_t;
typedef __attribute__((address_space(3))) unsigned int*       gldlds_dst_t;

// ---------------------------------------------------------------------------
// K1: coalesced async stage (global_load_lds) -> LDS -> gather+exp.
// One block = 8 consecutive (t,b) rows (same t, b0..b0+7; 8 divides 48).
// em layout [B][T][EMS]: em[b][t][0]=p_blank, em[b][t][2+j]=p(tg[b][j]).
// ---------------------------------------------------------------------------
__global__ __launch_bounds__(256) void ctc_gather_kernel(
    const float* __restrict__ lp,
    const int* __restrict__ targets,
    float* __restrict__ em)
{
  __shared__ float rb[8000];                   // 8 rows x 1000 floats
  const int tid  = threadIdx.x;
  const int wv   = tid >> 6;
  const int lane = tid & 63;
  const size_t row0 = (size_t)blockIdx.x * 8;

  const float4* src = (const float4*)(lp + row0 * VV);   // 2000 float4, contiguous
#pragma unroll
  for (int i = 0; i < 8; i++) {
    int idx = tid + (i << 8);                  // f4 index; lane-contiguous per wave
    if (idx < 2000)
      __builtin_amdgcn_global_load_lds(
          (gldlds_src_t)(src + idx),
          (gldlds_dst_t)(rb + ((size_t)((i << 8) + (wv << 6)) << 2)),
          16, 0, 0);
  }
  __syncthreads();                             // drains vmcnt

  const int t  = (int)(row0 / BB);
  const int b0 = (int)(row0 % BB);
#pragma unroll
  for (int r = 0; r < 2; r++) {
    const int bl = 2 * wv + r;                 // local row 0..7
    const int b  = b0 + bl;
    const int* __restrict__ tg = targets + b * LL;
    const float* row = rb + bl * 1000;
    const int g0 = (lane == 0) ? 0 : tg[lane - 1];   // gather idx k=lane
    const int g1 = tg[lane + 63];                    // k = lane+64
    float v0 = row[g0];
    float v1 = row[g1];
    float* erow = em + (size_t)b * EMTOT + (size_t)t * EMS;
    erow[(lane == 0) ? 0 : (lane + 1)] = __expf(v0);
    erow[lane + 65] = __expf(v1);
    if (lane == 0) erow[129] = __expf(row[tg[127]]);
  }
}

// ---------------------------------------------------------------------------
// K2: linear-domain scaled CTC forward. One block (4 waves) per batch element.
// Waves 1-3: async-stage 60-step emission tiles (global_load_lds, dbuf LDS).
// Wave 0: DP recurrence, states s = 4*lane + r (+ s=256 as a4 on lane 63).
// Cross-lane via DPP (no lgkmcnt). Rescale is deferred one 4-step group so
// the DPP max-reduce latency hides behind the next group's STEPs (powers of
// 2 commute exactly through the linear recurrence).
// ---------------------------------------------------------------------------
__global__ __launch_bounds__(256) void ctc_dp_kernel(
    const float* __restrict__ em,
    const int* __restrict__ targets,
    const int* __restrict__ input_lengths,
    float* __restrict__ out)
{
  __shared__ float sbuf[2][TILEF];             // 63360 B
  const int b    = blockIdx.x;
  const int lane = threadIdx.x & 63;
  const int wv   = threadIdx.x >> 6;
  const int NS   = input_lengths[b] - 1;       // steps t = 1..NS
  const float* __restrict__ base = em + (size_t)b * EMTOT;

  // ----- consumer lane-local constants -----
  float skip1 = 0.f, skip3 = 0.f, m63 = 0.f, sel1648 = 0.f, sel32 = 0.f;
  if (wv == 0) {
    const int* __restrict__ tg = targets + b * LL;
    const int c0  = tg[2 * lane];
    const int c1  = tg[2 * lane + 1];
    const int cm1 = (lane > 0) ? tg[2 * lane - 1] : c0;
    skip1   = (lane > 0 && c0 != cm1) ? 1.0f : 0.0f;
    skip3   = (c1 != c0) ? 1.0f : 0.0f;
    m63     = (lane == 63) ? 1.0f : 0.0f;
    sel1648 = (lane == 16 || lane == 48) ? 1.0f : 0.0f;
    sel32   = (lane == 32) ? 1.0f : 0.0f;
  }

  float a0 = 0.f, a1 = 0.f, a2 = 0.f, a3 = 0.f, a4 = 0.f;
  int esum = 0;
  float sc_p = 1.0f;                           // pending (deferred) scale
  int   se_p = 0;
  float  pb_r[4];
  float2 ev_r[4];

  // 3 producer waves split the 31 64-f4 groups round-robin.
#define STAGE(KN) do {                                               \
    const float4* src_ = (const float4*)(base + (size_t)(KN) * TILEF); \
    float* dst_ = sbuf[(KN) & 1];                                    \
    const int nf4_ = ((KN) == NTILES - 1) ? 1320 : 1980;             \
    for (int j = wv - 1; j < 31; j += 3) {                           \
      int idx_ = (j << 6) + lane;                                    \
      if (idx_ < nf4_)                                               \
        __builtin_amdgcn_global_load_lds(                            \
            (gldlds_src_t)(src_ + idx_),                             \
            (gldlds_dst_t)(dst_ + (j << 8)), 16, 0, 0);              \
    }                                                                \
  } while (0)

  // alpha_old[4l-1]: DPP row_shr:1 (row-edge lanes -> 0), patch lanes 16/48
  // from row_bcast15 and lane 32 from row_bcast31.
#define STEP(PB, EV) do {                                            \
    float am1 = DPPF(a3, 0x111);                                     \
    float h15 = DPPF(a3, 0x142);                                     \
    float h31 = DPPF(a3, 0x143);                                     \
    am1 = fmaf(sel1648, h15, am1);                                   \
    am1 = fmaf(sel32,   h31, am1);                                   \
    float s0 = a0 + am1;                                             \
    float s1 = fmaf(skip1, am1, a0 + a1);                            \
    float s2 = a1 + a2;                                              \
    float s3 = fmaf(skip3, a1, a2 + a3);                             \
    float s4 = fmaf(a3, m63, a4);                                    \
    a0 = s0 * (PB); a1 = s1 * (EV).x; a2 = s2 * (PB);                \
    a3 = s3 * (EV).y; a4 = s4 * (PB);                                \
  } while (0)

  // Apply previous group's scale, then start this group's max-reduce; the
  // result is consumed only one group later (latency hidden).
#define RESCALE_DEFERRED() do {                                      \
    a0 *= sc_p; a1 *= sc_p; a2 *= sc_p; a3 *= sc_p; a4 *= sc_p;      \
    esum -= se_p;                                                    \
    float mx = fmaxf(fmaxf(fmaxf(a0, a1), fmaxf(a2, a3)), a4);       \
    mx = fmaxf(mx, DPPF(mx, 0x111));                                 \
    mx = fmaxf(mx, DPPF(mx, 0x112));                                 \
    mx = fmaxf(mx, DPPF(mx, 0x114));                                 \
    mx = fmaxf(mx, DPPF(mx, 0x118));                                 \
    mx = fmaxf(mx, DPPF(mx, 0x142));                                 \
    mx = fmaxf(mx, DPPF(mx, 0x143));     /* lane63 = wave max */     \
    int eb = (__builtin_amdgcn_readlane(__float_as_int(mx), 63) >> 23) & 0xFF; \
    int se = 157 - eb;                   /* aim max at ~2^30 */      \
    se = se < -126 ? -126 : (se > 127 ? 127 : se);                   \
    sc_p = __uint_as_float((unsigned)(se + 127) << 23);              \
    se_p = se;                                                       \
  } while (0)

  if (wv) STAGE(0);
  __syncthreads();

  for (int k = 0; k < NTILES; k++) {
    if (wv) {
      if (k + 1 < NTILES) STAGE(k + 1);
    } else {
      const float* lb = sbuf[k & 1];
      if (k == 0 && lane == 0) { a0 = lb[0]; a1 = lb[2]; }  // t=0 init
      int tbeg = (k == 0) ? 1 : k * TILE;
      int tend = k * TILE + TILE - 1;
      if (tend > NS) tend = NS;
      int n = tend - tbeg + 1;
      if (n > 0) {
        const float* lb0 = lb + (tbeg - k * TILE) * EMS;
        const float* lbe = lb0 + 2 + 2 * lane;
#define LOADSLOT(D, TF) do {                                         \
    int off_ = (TF) * EMS;                                           \
    pb_r[D] = lb0[off_];                                             \
    ev_r[D] = *(const float2*)(lbe + off_);                          \
  } while (0)
#pragma unroll
        for (int d = 0; d < 4; d++) { if (d < n) LOADSLOT(d, d); }
        int i = 0;
        while (i + 4 <= n) {
#pragma unroll
          for (int d = 0; d < 4; d++) {
            STEP(pb_r[d], ev_r[d]);
            int tf = i + 4 + d;
            if (tf < n) LOADSLOT(d, tf);
          }
          RESCALE_DEFERRED();
          i += 4;
        }
#pragma unroll
        for (int d = 0; d < 3; d++) {
          if (i + d < n) STEP(pb_r[d], ev_r[d]);
        }
#undef LOADSLOT
      }
    }
    __syncthreads();
  }

  if (wv == 0 && lane == 63) {
    a3 *= sc_p; a4 *= sc_p; esum -= se_p;      // flush pending scale
    // alpha[255] = a3, alpha[256] = a4 (true value = stored * 2^esum)
    float tot = __logf(a3 + a4) + (float)esum * 0.69314718055994530942f;
    atomicAdd(out, -tot);
  }
#undef STEP
#undef RESCALE_DEFERRED
#undef STAGE
}

// ---------------------------------------------------------------------------
extern "C" void kernel_launch(void* const* d_in, const int* in_sizes, int n_in,
                              void* d_out, int out_size, void* d_ws, size_t ws_size,
                              hipStream_t stream) {
  const float* lp            = (const float*)d_in[0];
  const int*   targets       = (const int*)d_in[1];
  const int*   input_lengths = (const int*)d_in[2];

  float* em  = (float*)d_ws;                   // BB*EMTOT floats = ~40.6 MB
  float* out = (float*)d_out;

  hipMemsetAsync(out, 0, sizeof(float), stream);

  ctc_gather_kernel<<<(TT * BB) / 8, 256, 0, stream>>>(lp, targets, em);
  ctc_dp_kernel<<<BB, 256, 0, stream>>>(em, targets, input_lengths, out);
}